// Round 5
// baseline (4692.213 us; speedup 1.0000x reference)
//
#include <hip/hip_runtime.h>

typedef _Float16 half8 __attribute__((ext_vector_type(8)));
typedef _Float16 half4v __attribute__((ext_vector_type(4)));
typedef float float4v __attribute__((ext_vector_type(4)));

#define HID 2048
#define EMBD 2048
#define BATCH 128
#define TSTEPS 256
#define STEP ((size_t)BATCH * HID)

// ---------------- small prep kernels ----------------
__global__ __launch_bounds__(256) void cast_f16_kernel(const float* __restrict__ src,
                                                       _Float16* __restrict__ dst, int n) {
    int i = (blockIdx.x * 256 + threadIdx.x) * 4;
    int stride = gridDim.x * 256 * 4;
    for (; i < n; i += stride) {
        float4v v = *(const float4v*)(src + i);
        half4v h;
        h[0] = (_Float16)v[0]; h[1] = (_Float16)v[1];
        h[2] = (_Float16)v[2]; h[3] = (_Float16)v[3];
        *(half4v*)(dst + i) = h;
    }
}

__global__ __launch_bounds__(256) void bias_kernel(const float* __restrict__ a,
                                                   const float* __restrict__ b,
                                                   float* __restrict__ dst) {
    int i = blockIdx.x * 256 + threadIdx.x;
    if (i < HID) dst[i] = a[i] + b[i];
}

// ---------------- Phase A: xproj = gather(emb,x) @ W_ih^T + bias ----------------
__global__ __launch_bounds__(256) void phaseA_kernel(const int* __restrict__ x,
                                                     const float* __restrict__ emb,
                                                     const _Float16* __restrict__ w16,
                                                     const float* __restrict__ bias,
                                                     _Float16* __restrict__ xproj) {
    __shared__ __align__(16) _Float16 As[128 * 64];
    __shared__ __align__(16) _Float16 Bs[128 * 64];

    const int tid = threadIdx.x;
    const int bx  = blockIdx.x;
    const int nt = bx & 15, mt = bx >> 4;
    const long m0 = (long)mt * 128;
    const long n0 = (long)nt * 128;
    const int lane = tid & 63, w = tid >> 6;
    const int ln15 = lane & 15, kg = lane >> 4;
    const int wr = (w >> 1) * 64, wc = (w & 1) * 64;

    int xr[4];
#pragma unroll
    for (int it = 0; it < 4; ++it) xr[it] = x[m0 + ((it * 256 + tid) >> 3)];

    float4v acc[4][4];
#pragma unroll
    for (int m = 0; m < 4; ++m)
#pragma unroll
        for (int n = 0; n < 4; ++n) acc[m][n] = (float4v){0.f, 0.f, 0.f, 0.f};

    for (int kt = 0; kt < 32; ++kt) {
        __syncthreads();
#pragma unroll
        for (int it = 0; it < 4; ++it) {
            int c = it * 256 + tid;
            const float* src = emb + (long)xr[it] * EMBD + kt * 64 + (c & 7) * 8;
            float4v v0 = *(const float4v*)src;
            float4v v1 = *(const float4v*)(src + 4);
            half8 hv;
#pragma unroll
            for (int q = 0; q < 4; ++q) { hv[q] = (_Float16)v0[q]; hv[4 + q] = (_Float16)v1[q]; }
            *(half8*)(&As[c * 8]) = hv;
        }
#pragma unroll
        for (int it = 0; it < 4; ++it) {
            int c = it * 256 + tid;
            const _Float16* src = w16 + (n0 + (c >> 3)) * (long)EMBD + kt * 64 + (c & 7) * 8;
            *(half8*)(&Bs[c * 8]) = *(const half8*)src;
        }
        __syncthreads();
#pragma unroll
        for (int kk = 0; kk < 2; ++kk) {
            half8 a[4], b[4];
#pragma unroll
            for (int m = 0; m < 4; ++m)
                a[m] = *(half8*)(&As[(wr + m * 16 + ln15) * 64 + kk * 32 + kg * 8]);
#pragma unroll
            for (int n = 0; n < 4; ++n)
                b[n] = *(half8*)(&Bs[(wc + n * 16 + ln15) * 64 + kk * 32 + kg * 8]);
            // swapped operands -> transposed fragment: lane holds 4 consecutive cols
#pragma unroll
            for (int m = 0; m < 4; ++m)
#pragma unroll
                for (int n = 0; n < 4; ++n)
                    acc[m][n] = __builtin_amdgcn_mfma_f32_16x16x32_f16(b[n], a[m], acc[m][n], 0, 0, 0);
        }
    }
#pragma unroll
    for (int m = 0; m < 4; ++m) {
        long mg = m0 + wr + m * 16 + ln15;
#pragma unroll
        for (int n = 0; n < 4; ++n) {
            int nb = (int)n0 + wc + n * 16 + kg * 4;
            float4v bv = *(const float4v*)(bias + nb);
            union { half4v h; unsigned long long u; } pk;
#pragma unroll
            for (int r = 0; r < 4; ++r) pk.h[r] = (_Float16)(acc[m][n][r] + bv[r]);
            *(unsigned long long*)(xproj + mg * HID + nb) = pk.u;
        }
    }
}

// ---------------- Phase B: persistent scan, barrier-free dataflow ----------------
// 256 blocks x 320 threads. gid=bx&3 owns rows [32*gid,+32); sub=bx>>2 owns cols
// [32*sub,+32). Waves 0-3 = compute quadrants (qr=w>>1 rows, qc=w&1 cols, full K);
// wave 4 = flag poller. h_{s+1} aliases into xproj[s]. All cross-block traffic is
// relaxed agent-scope (sc1 bypass, zero cache maintenance). No __syncthreads in loop.
// Producer wave: 8B bypass h-store -> s_waitcnt vmcnt(0) -> per-wave flag store.
// Poller: streams group's 256 flags, publishes min per (qr, superchunk16) to LDS.
// Consumer: spins on LDS flag per k-superchunk (128 k = 4 producer blocks), so no
// cacheline first-touch race (128B line is within one superchunk).
__global__ __launch_bounds__(320, 1) void scan_kernel(_Float16* __restrict__ xproj,
                                                      const _Float16* __restrict__ whh,
                                                      float* __restrict__ hlast,
                                                      unsigned* __restrict__ flags) {
    __shared__ __align__(16) _Float16 Wl[32 * 2048];  // 128 KB
    __shared__ unsigned ldsflag[32];                  // [qr][g16] published mins

    const int tid = threadIdx.x;
    const int bx = blockIdx.x;
    const int gid = bx & 3;
    const int sub = bx >> 2;
    const int m0 = gid * 32;
    const int n0 = sub * 32;
    const int lane = tid & 63, w = tid >> 6;
    const int ln15 = lane & 15, kg = lane >> 4;

    // stage W[n0..n0+32) x [0..2048): byte = col*4096 + ((k*2) ^ ((col&7)<<4))
    for (int c = tid; c < 8192; c += 320) {
        int col = c >> 8, ch = c & 255;
        half8 v = *(const half8*)(whh + (long)(n0 + col) * HID + ch * 8);
        *(half8*)((char*)Wl + col * 4096 + ((ch * 16) ^ ((col & 7) << 4))) = v;
    }
    if (tid < 32) ldsflag[tid] = 0;
    __syncthreads();

    unsigned* gfl = flags + gid * 256;

    if (w == 4) {
        // ---- poller wave: lane l covers flags [8l, 8l+8) = (qr=l>>4, g16=l&15)
        if (lane < 32) {
            const unsigned long long* fp = (const unsigned long long*)gfl + (size_t)lane * 4;
            unsigned m = 0;
            while (m < TSTEPS - 1) {
                unsigned long long v0 = __hip_atomic_load(fp + 0, __ATOMIC_RELAXED, __HIP_MEMORY_SCOPE_AGENT);
                unsigned long long v1 = __hip_atomic_load(fp + 1, __ATOMIC_RELAXED, __HIP_MEMORY_SCOPE_AGENT);
                unsigned long long v2 = __hip_atomic_load(fp + 2, __ATOMIC_RELAXED, __HIP_MEMORY_SCOPE_AGENT);
                unsigned long long v3 = __hip_atomic_load(fp + 3, __ATOMIC_RELAXED, __HIP_MEMORY_SCOPE_AGENT);
                unsigned a0 = (unsigned)v0, a1 = (unsigned)(v0 >> 32);
                unsigned a2 = (unsigned)v1, a3 = (unsigned)(v1 >> 32);
                unsigned a4 = (unsigned)v2, a5 = (unsigned)(v2 >> 32);
                unsigned a6 = (unsigned)v3, a7 = (unsigned)(v3 >> 32);
                unsigned mn = min(min(min(a0, a1), min(a2, a3)), min(min(a4, a5), min(a6, a7)));
                m = mn;
                __hip_atomic_store(&ldsflag[lane], m, __ATOMIC_RELAXED, __HIP_MEMORY_SCOPE_WORKGROUP);
            }
        }
        return;
    }

    const int qr = w >> 1, qc = w & 1;
    const size_t arow = (size_t)(m0 + qr * 16 + ln15);   // h row (load & store & bias)
    const int wbyte = (qc * 16 + ln15) * 4096;           // W LDS row base
    const int swz = (ln15 & 7) << 4;
    const int ocol = n0 + qc * 16 + kg * 4;              // output col base (4 wide)
    const int fidx = qr * 128 + (sub >> 2) * 8 + (sub & 3) * 2 + qc;
    unsigned* myflags = &ldsflag[qr * 16];

    for (int s = 0; s < TSTEPS; ++s) {
        // bias prefetch (bypass; same address this thread stores h_{s+1} to later)
        unsigned long long xbits = __hip_atomic_load(
            (const unsigned long long*)(xproj + (size_t)s * STEP + arow * HID + ocol),
            __ATOMIC_RELAXED, __HIP_MEMORY_SCOPE_AGENT);

        float4v acc = (float4v){0.f, 0.f, 0.f, 0.f};
        if (s > 0) {
            const _Float16* hrow = xproj + (size_t)(s - 1) * STEP + arow * HID;
            for (int j = 0; j < 16; ++j) {
                while (__hip_atomic_load(&myflags[j], __ATOMIC_ACQUIRE,
                                         __HIP_MEMORY_SCOPE_WORKGROUP) < (unsigned)s) {}
                __builtin_amdgcn_sched_barrier(0);
#pragma unroll
                for (int ki = 0; ki < 4; ++ki) {
                    int k = j * 128 + ki * 32;
                    half8 a = *(const half8*)(hrow + k + kg * 8);
                    half8 b = *(half8*)((char*)Wl + wbyte + ((k * 2 + kg * 16) ^ swz));
                    acc = __builtin_amdgcn_mfma_f32_16x16x32_f16(b, a, acc, 0, 0, 0);
                }
            }
        }

        union { unsigned long long u; half4v h; } xb; xb.u = xbits;
        float o0 = tanhf(acc[0] + (float)xb.h[0]);
        float o1 = tanhf(acc[1] + (float)xb.h[1]);
        float o2 = tanhf(acc[2] + (float)xb.h[2]);
        float o3 = tanhf(acc[3] + (float)xb.h[3]);

        if (s < TSTEPS - 1) {
            union { half4v h; unsigned long long u; } pk;
            pk.h[0] = (_Float16)o0; pk.h[1] = (_Float16)o1;
            pk.h[2] = (_Float16)o2; pk.h[3] = (_Float16)o3;
            __hip_atomic_store((unsigned long long*)(xproj + (size_t)s * STEP + arow * HID + ocol),
                               pk.u, __ATOMIC_RELAXED, __HIP_MEMORY_SCOPE_AGENT);
            asm volatile("s_waitcnt vmcnt(0)" ::: "memory");  // h at L3 before flag
            if (lane == 0)
                __hip_atomic_store(&gfl[fidx], (unsigned)(s + 1),
                                   __ATOMIC_RELAXED, __HIP_MEMORY_SCOPE_AGENT);
        } else {
            float4v f = {o0, o1, o2, o3};
            *(float4v*)(hlast + arow * HID + ocol) = f;
        }
    }
}

// ---------------- head ----------------
__global__ __launch_bounds__(256) void fc1_kernel(const float* __restrict__ hlast,
                                                  const float* __restrict__ w,
                                                  const float* __restrict__ b,
                                                  float* __restrict__ z) {
    int bb = blockIdx.x;
    int j = threadIdx.x;
    const float* hr = hlast + (long)bb * HID;
    const float* wr = w + (long)j * HID;
    float acc = 0.f;
    for (int k = 0; k < HID; k += 4) {
        float4v hv = *(const float4v*)(hr + k);
        float4v wv = *(const float4v*)(wr + k);
        acc += hv[0] * wv[0] + hv[1] * wv[1] + hv[2] * wv[2] + hv[3] * wv[3];
    }
    acc += b[j];
    z[bb * 256 + j] = fmaxf(acc, 0.f);
}

__global__ __launch_bounds__(256) void fc2_kernel(const float* __restrict__ z,
                                                  const float* __restrict__ w,
                                                  const float* __restrict__ b,
                                                  float* __restrict__ out) {
    __shared__ float red[4];
    int bb = blockIdx.x;
    int tid = threadIdx.x;
    float zv = z[bb * 256 + tid];
    for (int c = 0; c < 3; ++c) {
        float s = zv * w[c * 256 + tid];
        for (int off = 32; off > 0; off >>= 1) s += __shfl_down(s, off, 64);
        if ((tid & 63) == 0) red[tid >> 6] = s;
        __syncthreads();
        if (tid == 0) out[bb * 3 + c] = red[0] + red[1] + red[2] + red[3] + b[c];
        __syncthreads();
    }
}

// ---------------- launch ----------------
extern "C" void kernel_launch(void* const* d_in, const int* in_sizes, int n_in,
                              void* d_out, int out_size, void* d_ws, size_t ws_size,
                              hipStream_t stream) {
    const int*   x    = (const int*)d_in[0];
    const float* emb  = (const float*)d_in[1];
    const float* Wih  = (const float*)d_in[2];
    const float* Whh  = (const float*)d_in[3];
    const float* bih  = (const float*)d_in[4];
    const float* bhh  = (const float*)d_in[5];
    const float* fc1w = (const float*)d_in[6];
    const float* fc1b = (const float*)d_in[7];
    const float* fc2w = (const float*)d_in[8];
    const float* fc2b = (const float*)d_in[9];
    float* out = (float*)d_out;

    char* ws = (char*)d_ws;
    size_t off = 0;
    _Float16* xproj = (_Float16*)(ws + off); off += (size_t)TSTEPS * BATCH * HID * 2;  // 134.2 MB
    _Float16* wih16 = (_Float16*)(ws + off); off += (size_t)HID * EMBD * 2;            // 8 MB
    _Float16* whh16 = (_Float16*)(ws + off); off += (size_t)HID * HID * 2;             // 8 MB
    float*    bias  = (float*)(ws + off);    off += (size_t)HID * 4;
    float*    hlast = (float*)(ws + off);    off += (size_t)BATCH * HID * 4;
    float*    z     = (float*)(ws + off);    off += (size_t)BATCH * 256 * 4;
    unsigned* flags = (unsigned*)(ws + off); off += 4 * 256 * 4;  // 4 KB

    hipMemsetAsync(flags, 0, 4 * 256 * 4, stream);

    cast_f16_kernel<<<4096, 256, 0, stream>>>(Wih, wih16, HID * EMBD);
    cast_f16_kernel<<<4096, 256, 0, stream>>>(Whh, whh16, HID * HID);
    bias_kernel<<<8, 256, 0, stream>>>(bih, bhh, bias);

    phaseA_kernel<<<4096, 256, 0, stream>>>(x, emb, wih16, bias, xproj);

    void* args[] = {(void*)&xproj, (void*)&whh16, (void*)&hlast, (void*)&flags};
    hipLaunchCooperativeKernel((const void*)scan_kernel, dim3(256), dim3(320), args, 0, stream);

    fc1_kernel<<<BATCH, 256, 0, stream>>>(hlast, fc1w, fc1b, z);
    fc2_kernel<<<BATCH, 256, 0, stream>>>(z, fc2w, fc2b, out);
}

// Round 6
// 3748.576 us; speedup vs baseline: 1.2517x; 1.2517x over previous
//
#include <hip/hip_runtime.h>

typedef _Float16 half8 __attribute__((ext_vector_type(8)));
typedef _Float16 half4v __attribute__((ext_vector_type(4)));
typedef float float4v __attribute__((ext_vector_type(4)));

#define HID 2048
#define EMBD 2048
#define BATCH 128
#define TSTEPS 256
#define STEP ((size_t)BATCH * HID)

// ---------------- small prep kernels ----------------
__global__ __launch_bounds__(256) void cast_f16_kernel(const float* __restrict__ src,
                                                       _Float16* __restrict__ dst, int n) {
    int i = (blockIdx.x * 256 + threadIdx.x) * 4;
    int stride = gridDim.x * 256 * 4;
    for (; i < n; i += stride) {
        float4v v = *(const float4v*)(src + i);
        half4v h;
        h[0] = (_Float16)v[0]; h[1] = (_Float16)v[1];
        h[2] = (_Float16)v[2]; h[3] = (_Float16)v[3];
        *(half4v*)(dst + i) = h;
    }
}

__global__ __launch_bounds__(256) void bias_kernel(const float* __restrict__ a,
                                                   const float* __restrict__ b,
                                                   float* __restrict__ dst) {
    int i = blockIdx.x * 256 + threadIdx.x;
    if (i < HID) dst[i] = a[i] + b[i];
}

// ---------------- Phase A: xproj = gather(emb,x) @ W_ih^T + bias ----------------
__global__ __launch_bounds__(256) void phaseA_kernel(const int* __restrict__ x,
                                                     const float* __restrict__ emb,
                                                     const _Float16* __restrict__ w16,
                                                     const float* __restrict__ bias,
                                                     _Float16* __restrict__ xproj) {
    __shared__ __align__(16) _Float16 As[128 * 64];
    __shared__ __align__(16) _Float16 Bs[128 * 64];

    const int tid = threadIdx.x;
    const int bx  = blockIdx.x;
    const int nt = bx & 15, mt = bx >> 4;
    const long m0 = (long)mt * 128;
    const long n0 = (long)nt * 128;
    const int lane = tid & 63, w = tid >> 6;
    const int ln15 = lane & 15, kg = lane >> 4;
    const int wr = (w >> 1) * 64, wc = (w & 1) * 64;

    int xr[4];
#pragma unroll
    for (int it = 0; it < 4; ++it) xr[it] = x[m0 + ((it * 256 + tid) >> 3)];

    float4v acc[4][4];
#pragma unroll
    for (int m = 0; m < 4; ++m)
#pragma unroll
        for (int n = 0; n < 4; ++n) acc[m][n] = (float4v){0.f, 0.f, 0.f, 0.f};

    for (int kt = 0; kt < 32; ++kt) {
        __syncthreads();
#pragma unroll
        for (int it = 0; it < 4; ++it) {
            int c = it * 256 + tid;
            const float* src = emb + (long)xr[it] * EMBD + kt * 64 + (c & 7) * 8;
            float4v v0 = *(const float4v*)src;
            float4v v1 = *(const float4v*)(src + 4);
            half8 hv;
#pragma unroll
            for (int q = 0; q < 4; ++q) { hv[q] = (_Float16)v0[q]; hv[4 + q] = (_Float16)v1[q]; }
            *(half8*)(&As[c * 8]) = hv;
        }
#pragma unroll
        for (int it = 0; it < 4; ++it) {
            int c = it * 256 + tid;
            const _Float16* src = w16 + (n0 + (c >> 3)) * (long)EMBD + kt * 64 + (c & 7) * 8;
            *(half8*)(&Bs[c * 8]) = *(const half8*)src;
        }
        __syncthreads();
#pragma unroll
        for (int kk = 0; kk < 2; ++kk) {
            half8 a[4], b[4];
#pragma unroll
            for (int m = 0; m < 4; ++m)
                a[m] = *(half8*)(&As[(wr + m * 16 + ln15) * 64 + kk * 32 + kg * 8]);
#pragma unroll
            for (int n = 0; n < 4; ++n)
                b[n] = *(half8*)(&Bs[(wc + n * 16 + ln15) * 64 + kk * 32 + kg * 8]);
            // swapped operands -> transposed fragment: lane holds 4 consecutive cols
#pragma unroll
            for (int m = 0; m < 4; ++m)
#pragma unroll
                for (int n = 0; n < 4; ++n)
                    acc[m][n] = __builtin_amdgcn_mfma_f32_16x16x32_f16(b[n], a[m], acc[m][n], 0, 0, 0);
        }
    }
#pragma unroll
    for (int m = 0; m < 4; ++m) {
        long mg = m0 + wr + m * 16 + ln15;
#pragma unroll
        for (int n = 0; n < 4; ++n) {
            int nb = (int)n0 + wc + n * 16 + kg * 4;
            float4v bv = *(const float4v*)(bias + nb);
            union { half4v h; unsigned long long u; } pk;
#pragma unroll
            for (int r = 0; r < 4; ++r) pk.h[r] = (_Float16)(acc[m][n][r] + bv[r]);
            *(unsigned long long*)(xproj + mg * HID + nb) = pk.u;
        }
    }
}

// ---------------- Phase B: persistent scan ----------------
// 256 blocks x 256 threads. gid=bx&3 owns rows [32*gid,+32); sub=bx>>2 owns cols
// [32*sub,+32). Wave (qr=w>>1, qc=w&1): 16 rows x 16 cols x full K.
// Protocol (R4-proven): h stores + bias reads + flags = relaxed agent (sc1 bypass,
// zero cache maintenance); h reads = plain cacheable first-touch loads (L2-shared
// across the XCD's 32 same-group blocks). h_{s+1} aliases into xproj[s].
// Barrier chain (new): every wave posts its flag after vmcnt(0); wave0 batch-polls
// all 256 group flags (2 u64/lane, paced by s_sleep) and relays via an LDS goflag;
// other waves spin on LDS. No __syncthreads, no RMW, no poller congestion.
__global__ __launch_bounds__(256, 1) void scan_kernel(_Float16* __restrict__ xproj,
                                                      const _Float16* __restrict__ whh,
                                                      float* __restrict__ hlast,
                                                      unsigned* __restrict__ flags) {
    __shared__ __align__(16) _Float16 Wl[32 * 2048];  // 128 KB
    __shared__ unsigned goflag;

    const int tid = threadIdx.x;
    const int bx = blockIdx.x;
    const int gid = bx & 3;
    const int sub = bx >> 2;
    const int m0 = gid * 32;
    const int n0 = sub * 32;
    const int lane = tid & 63, w = tid >> 6;
    const int ln15 = lane & 15, kg = lane >> 4;

    // stage W[n0..n0+32) x [0..2048): byte = col*4096 + ((k*2) ^ ((col&7)<<4))
    for (int it = 0; it < 32; ++it) {
        int c = it * 256 + tid;
        int col = c >> 8, ch = c & 255;
        half8 v = *(const half8*)(whh + (long)(n0 + col) * HID + ch * 8);
        *(half8*)((char*)Wl + col * 4096 + ((ch * 16) ^ ((col & 7) << 4))) = v;
    }
    if (tid == 0) goflag = 0;
    __syncthreads();

    unsigned* gfl = flags + gid * 256;                       // 256 u32 per group
    const unsigned long long* gfl64 = (const unsigned long long*)gfl;
    const int qr = w >> 1, qc = w & 1;
    const size_t arow = (size_t)(m0 + qr * 16 + ln15);       // h row (load/store/bias)
    const int wbyte = (qc * 16 + ln15) * 4096;               // W LDS row base
    const int swz = (ln15 & 7) << 4;
    const int ocol = n0 + qc * 16 + kg * 4;                  // output col base (4 wide)
    const int fidx = qr * 128 + sub * 2 + qc;                // this wave's flag slot

    for (int s = 0; s < TSTEPS; ++s) {
        // bias prefetch (bypass; same thread later stores h_{s+1} to this address)
        unsigned long long xbits = __hip_atomic_load(
            (const unsigned long long*)(xproj + (size_t)s * STEP + arow * HID + ocol),
            __ATOMIC_RELAXED, __HIP_MEMORY_SCOPE_AGENT);

        float4v acc0 = (float4v){0.f, 0.f, 0.f, 0.f};
        float4v acc1 = (float4v){0.f, 0.f, 0.f, 0.f};
        if (s > 0) {
            if (w == 0) {
                // batched poll: lane covers 4 flags (2 u64), whole group in one round
                for (;;) {
                    unsigned long long v0 = __hip_atomic_load(gfl64 + lane,
                                             __ATOMIC_RELAXED, __HIP_MEMORY_SCOPE_AGENT);
                    unsigned long long v1 = __hip_atomic_load(gfl64 + 64 + lane,
                                             __ATOMIC_RELAXED, __HIP_MEMORY_SCOPE_AGENT);
                    bool ok = ((unsigned)v0 >= (unsigned)s) && ((unsigned)(v0 >> 32) >= (unsigned)s) &&
                              ((unsigned)v1 >= (unsigned)s) && ((unsigned)(v1 >> 32) >= (unsigned)s);
                    if (__all(ok)) break;
                    __builtin_amdgcn_s_sleep(2);
                }
                __hip_atomic_store(&goflag, (unsigned)s, __ATOMIC_RELAXED,
                                   __HIP_MEMORY_SCOPE_WORKGROUP);
            } else {
                while (__hip_atomic_load(&goflag, __ATOMIC_RELAXED,
                                         __HIP_MEMORY_SCOPE_WORKGROUP) < (unsigned)s)
                    __builtin_amdgcn_s_sleep(1);
            }
            __builtin_amdgcn_sched_barrier(0);

            // flat unrolled K loop: compiler hoists independent h loads deep
            const _Float16* hrow = xproj + (size_t)(s - 1) * STEP + arow * HID;
#pragma unroll
            for (int j = 0; j < 64; ++j) {
                int k = j * 32;
                half8 a = *(const half8*)(hrow + k + kg * 8);
                half8 b = *(half8*)((char*)Wl + wbyte + ((k * 2 + kg * 16) ^ swz));
                if (j & 1) acc1 = __builtin_amdgcn_mfma_f32_16x16x32_f16(b, a, acc1, 0, 0, 0);
                else       acc0 = __builtin_amdgcn_mfma_f32_16x16x32_f16(b, a, acc0, 0, 0, 0);
            }
        }

        union { unsigned long long u; half4v h; } xb; xb.u = xbits;
        float o0 = tanhf(acc0[0] + acc1[0] + (float)xb.h[0]);
        float o1 = tanhf(acc0[1] + acc1[1] + (float)xb.h[1]);
        float o2 = tanhf(acc0[2] + acc1[2] + (float)xb.h[2]);
        float o3 = tanhf(acc0[3] + acc1[3] + (float)xb.h[3]);

        if (s < TSTEPS - 1) {
            union { half4v h; unsigned long long u; } pk;
            pk.h[0] = (_Float16)o0; pk.h[1] = (_Float16)o1;
            pk.h[2] = (_Float16)o2; pk.h[3] = (_Float16)o3;
            __hip_atomic_store((unsigned long long*)(xproj + (size_t)s * STEP + arow * HID + ocol),
                               pk.u, __ATOMIC_RELAXED, __HIP_MEMORY_SCOPE_AGENT);
            asm volatile("s_waitcnt vmcnt(0)" ::: "memory");  // h acked before flag
            if (lane == 0)
                __hip_atomic_store(&gfl[fidx], (unsigned)(s + 1),
                                   __ATOMIC_RELAXED, __HIP_MEMORY_SCOPE_AGENT);
        } else {
            float4v f = {o0, o1, o2, o3};
            *(float4v*)(hlast + arow * HID + ocol) = f;
        }
    }
}

// ---------------- head ----------------
__global__ __launch_bounds__(64) void fc1_kernel(const float* __restrict__ hlast,
                                                 const float* __restrict__ w,
                                                 const float* __restrict__ b,
                                                 float* __restrict__ z) {
    int bb = blockIdx.x;
    int j = blockIdx.y * 64 + threadIdx.x;
    const float* hr = hlast + (long)bb * HID;
    const float* wr = w + (long)j * HID;
    float acc = 0.f;
    for (int k = 0; k < HID; k += 4) {
        float4v hv = *(const float4v*)(hr + k);
        float4v wv = *(const float4v*)(wr + k);
        acc += hv[0] * wv[0] + hv[1] * wv[1] + hv[2] * wv[2] + hv[3] * wv[3];
    }
    acc += b[j];
    z[bb * 256 + j] = fmaxf(acc, 0.f);
}

__global__ __launch_bounds__(256) void fc2_kernel(const float* __restrict__ z,
                                                  const float* __restrict__ w,
                                                  const float* __restrict__ b,
                                                  float* __restrict__ out) {
    __shared__ float red[4];
    int bb = blockIdx.x;
    int tid = threadIdx.x;
    float zv = z[bb * 256 + tid];
    for (int c = 0; c < 3; ++c) {
        float s = zv * w[c * 256 + tid];
        for (int off = 32; off > 0; off >>= 1) s += __shfl_down(s, off, 64);
        if ((tid & 63) == 0) red[tid >> 6] = s;
        __syncthreads();
        if (tid == 0) out[bb * 3 + c] = red[0] + red[1] + red[2] + red[3] + b[c];
        __syncthreads();
    }
}

// ---------------- launch ----------------
extern "C" void kernel_launch(void* const* d_in, const int* in_sizes, int n_in,
                              void* d_out, int out_size, void* d_ws, size_t ws_size,
                              hipStream_t stream) {
    const int*   x    = (const int*)d_in[0];
    const float* emb  = (const float*)d_in[1];
    const float* Wih  = (const float*)d_in[2];
    const float* Whh  = (const float*)d_in[3];
    const float* bih  = (const float*)d_in[4];
    const float* bhh  = (const float*)d_in[5];
    const float* fc1w = (const float*)d_in[6];
    const float* fc1b = (const float*)d_in[7];
    const float* fc2w = (const float*)d_in[8];
    const float* fc2b = (const float*)d_in[9];
    float* out = (float*)d_out;

    char* ws = (char*)d_ws;
    size_t off = 0;
    _Float16* xproj = (_Float16*)(ws + off); off += (size_t)TSTEPS * BATCH * HID * 2;  // 134.2 MB
    _Float16* wih16 = (_Float16*)(ws + off); off += (size_t)HID * EMBD * 2;            // 8 MB
    _Float16* whh16 = (_Float16*)(ws + off); off += (size_t)HID * HID * 2;             // 8 MB
    float*    bias  = (float*)(ws + off);    off += (size_t)HID * 4;
    float*    hlast = (float*)(ws + off);    off += (size_t)BATCH * HID * 4;
    float*    z     = (float*)(ws + off);    off += (size_t)BATCH * 256 * 4;
    unsigned* flags = (unsigned*)(ws + off); off += 4 * 256 * 4;  // 4 KB

    hipMemsetAsync(flags, 0, 4 * 256 * 4, stream);

    cast_f16_kernel<<<4096, 256, 0, stream>>>(Wih, wih16, HID * EMBD);
    cast_f16_kernel<<<4096, 256, 0, stream>>>(Whh, whh16, HID * HID);
    bias_kernel<<<8, 256, 0, stream>>>(bih, bhh, bias);

    phaseA_kernel<<<4096, 256, 0, stream>>>(x, emb, wih16, bias, xproj);

    void* args[] = {(void*)&xproj, (void*)&whh16, (void*)&hlast, (void*)&flags};
    hipLaunchCooperativeKernel((const void*)scan_kernel, dim3(256), dim3(256), args, 0, stream);

    fc1_kernel<<<dim3(128, 4), 64, 0, stream>>>(hlast, fc1w, fc1b, z);
    fc2_kernel<<<BATCH, 256, 0, stream>>>(z, fc2w, fc2b, out);
}

// Round 8
// 3012.303 us; speedup vs baseline: 1.5577x; 1.2444x over previous
//
#include <hip/hip_runtime.h>

typedef _Float16 half8 __attribute__((ext_vector_type(8)));
typedef _Float16 half4v __attribute__((ext_vector_type(4)));
typedef float float4v __attribute__((ext_vector_type(4)));

#define HID 2048
#define EMBD 2048
#define BATCH 128
#define TSTEPS 256
#define STEP ((size_t)BATCH * HID)
#define SENT 0xFFFFFFFFFFFFFFFFull

// relaxed agent-scope (sc1 bypass) u64 load of h-chunk j (32 halves/chunk = 8 u64), half hh
#define LDH(hp, j, hh) __hip_atomic_load((hp) + (j) * 8 + (hh), __ATOMIC_RELAXED, __HIP_MEMORY_SCOPE_AGENT)

// ---------------- small prep kernels ----------------
__global__ __launch_bounds__(256) void cast_f16_kernel(const float* __restrict__ src,
                                                       _Float16* __restrict__ dst, int n) {
    int i = (blockIdx.x * 256 + threadIdx.x) * 4;
    int stride = gridDim.x * 256 * 4;
    for (; i < n; i += stride) {
        float4v v = *(const float4v*)(src + i);
        half4v h;
        h[0] = (_Float16)v[0]; h[1] = (_Float16)v[1];
        h[2] = (_Float16)v[2]; h[3] = (_Float16)v[3];
        *(half4v*)(dst + i) = h;
    }
}

__global__ __launch_bounds__(256) void bias_kernel(const float* __restrict__ a,
                                                   const float* __restrict__ b,
                                                   float* __restrict__ dst) {
    int i = blockIdx.x * 256 + threadIdx.x;
    if (i < HID) dst[i] = a[i] + b[i];
}

// ---------------- Phase A: xbias = gather(emb,x) @ W_ih^T + bias ----------------
__global__ __launch_bounds__(256) void phaseA_kernel(const int* __restrict__ x,
                                                     const float* __restrict__ emb,
                                                     const _Float16* __restrict__ w16,
                                                     const float* __restrict__ bias,
                                                     _Float16* __restrict__ xbias) {
    __shared__ __align__(16) _Float16 As[128 * 64];
    __shared__ __align__(16) _Float16 Bs[128 * 64];

    const int tid = threadIdx.x;
    const int bx  = blockIdx.x;
    const int nt = bx & 15, mt = bx >> 4;
    const long m0 = (long)mt * 128;
    const long n0 = (long)nt * 128;
    const int lane = tid & 63, w = tid >> 6;
    const int ln15 = lane & 15, kg = lane >> 4;
    const int wr = (w >> 1) * 64, wc = (w & 1) * 64;

    int xr[4];
#pragma unroll
    for (int it = 0; it < 4; ++it) xr[it] = x[m0 + ((it * 256 + tid) >> 3)];

    float4v acc[4][4];
#pragma unroll
    for (int m = 0; m < 4; ++m)
#pragma unroll
        for (int n = 0; n < 4; ++n) acc[m][n] = (float4v){0.f, 0.f, 0.f, 0.f};

    for (int kt = 0; kt < 32; ++kt) {
        __syncthreads();
#pragma unroll
        for (int it = 0; it < 4; ++it) {
            int c = it * 256 + tid;
            const float* src = emb + (long)xr[it] * EMBD + kt * 64 + (c & 7) * 8;
            float4v v0 = *(const float4v*)src;
            float4v v1 = *(const float4v*)(src + 4);
            half8 hv;
#pragma unroll
            for (int q = 0; q < 4; ++q) { hv[q] = (_Float16)v0[q]; hv[4 + q] = (_Float16)v1[q]; }
            *(half8*)(&As[c * 8]) = hv;
        }
#pragma unroll
        for (int it = 0; it < 4; ++it) {
            int c = it * 256 + tid;
            const _Float16* src = w16 + (n0 + (c >> 3)) * (long)EMBD + kt * 64 + (c & 7) * 8;
            *(half8*)(&Bs[c * 8]) = *(const half8*)src;
        }
        __syncthreads();
#pragma unroll
        for (int kk = 0; kk < 2; ++kk) {
            half8 a[4], b[4];
#pragma unroll
            for (int m = 0; m < 4; ++m)
                a[m] = *(half8*)(&As[(wr + m * 16 + ln15) * 64 + kk * 32 + kg * 8]);
#pragma unroll
            for (int n = 0; n < 4; ++n)
                b[n] = *(half8*)(&Bs[(wc + n * 16 + ln15) * 64 + kk * 32 + kg * 8]);
            // swapped operands -> transposed fragment: lane holds 4 consecutive cols
#pragma unroll
            for (int m = 0; m < 4; ++m)
#pragma unroll
                for (int n = 0; n < 4; ++n)
                    acc[m][n] = __builtin_amdgcn_mfma_f32_16x16x32_f16(b[n], a[m], acc[m][n], 0, 0, 0);
        }
    }
#pragma unroll
    for (int m = 0; m < 4; ++m) {
        long mg = m0 + wr + m * 16 + ln15;
#pragma unroll
        for (int n = 0; n < 4; ++n) {
            int nb = (int)n0 + wc + n * 16 + kg * 4;
            float4v bv = *(const float4v*)(bias + nb);
            union { half4v h; unsigned long long u; } pk;
#pragma unroll
            for (int r = 0; r < 4; ++r) pk.h[r] = (_Float16)(acc[m][n][r] + bv[r]);
            *(unsigned long long*)(xbias + mg * HID + nb) = pk.u;
        }
    }
}

// ---------------- Phase B: persistent scan, sentinel dataflow (NO flags/barriers) ----
// 256 blocks x 256 thr. gid=bx&3 owns rows [32g,+32); sub=bx>>2 owns cols [32c,+32).
// Wave (pr=w>>1, kh=w&1): 16 rows x 32 cols x k-half; LDS part-reduce (stride 33).
// h ring: 8 step-slots, pre-poisoned 0xFF. Step s: reads h_s from slot (s-1)&7 via
// sc1 data-poll (retry while u64==SENT; 4xNaN impossible as tanh output); stores
// h_{s+1} to slot s&7 (fire-and-forget sc1); lazily poisons slot (s+4)&7 (content
// h_{s-3}, readers were at step s-3; within-group drift<=1 by data dependency so a
// poisoner at s would need h_{s-1} which a reader-at-(s-3) hasn't produced ->
// impossible to poison under a live reader). vmcnt(0) before each store-section
// orders poison(slot) < next h-store(slot) at L3 => staleness provably impossible.
// xbias is read-only -> plain cacheable loads.
__global__ __launch_bounds__(256, 1) void scan_kernel(const _Float16* __restrict__ xbias,
                                                      const _Float16* __restrict__ whh,
                                                      _Float16* __restrict__ ring,
                                                      float* __restrict__ hlast) {
    __shared__ __align__(16) _Float16 Wl[32 * 2048];  // 128 KB
    __shared__ float part[4][16 * 33];

    const int tid = threadIdx.x;
    const int bx = blockIdx.x;
    const int gid = bx & 3, sub = bx >> 2;
    const int m0 = gid * 32, n0 = sub * 32;
    const int lane = tid & 63, w = tid >> 6;
    const int ln15 = lane & 15, kg = lane >> 4;
    const int pr = w >> 1, kh = w & 1;

    // stage W[n0..n0+32) x [0..2048): byte = col*4096 + ((k*2) ^ ((col&7)<<4))
    for (int it = 0; it < 32; ++it) {
        int c = it * 256 + tid;
        int col = c >> 8, ch = c & 255;
        half8 v = *(const half8*)(whh + (long)(n0 + col) * HID + ch * 8);
        *(half8*)((char*)Wl + col * 4096 + ((ch * 16) ^ ((col & 7) << 4))) = v;
    }
    __syncthreads();

    const size_t arow = (size_t)(m0 + pr * 16 + ln15);   // h row this lane loads
    const int wb0 = ln15 * 4096;                          // W LDS row bases (cols)
    const int wb1 = (16 + ln15) * 4096;
    const int swz = (ln15 & 7) << 4;
    const int kb = kh * 2048;                             // k-half byte offset in W row
    // reduce/output mapping
    const int rp = tid >> 7, ridx = tid & 127;
    const int rrow = ridx >> 3, rc4 = (ridx & 7) * 4;
    const size_t oidx = (size_t)(m0 + rp * 16 + rrow) * HID + n0 + rc4;

    for (int s = 0; s < TSTEPS; ++s) {
        // bias: plain cacheable load (xbias never overwritten)
        half4v xpv = *(const half4v*)(xbias + (size_t)s * STEP + oidx);

        float4v acc0 = (float4v){0.f, 0.f, 0.f, 0.f};
        float4v acc1 = (float4v){0.f, 0.f, 0.f, 0.f};
        if (s > 0) {
            const unsigned long long* hp = (const unsigned long long*)
                (ring + (size_t)((s - 1) & 7) * STEP + arow * HID + kh * 1024 + kg * 8);
            // 4 batches x 8 chunks, double-buffered: straight-line issue keeps
            // 16 relaxed loads in flight (counted vmcnt), retry only on sentinel.
            unsigned long long va[8][2], vb[8][2];
#pragma unroll
            for (int q = 0; q < 8; ++q) { va[q][0] = LDH(hp, q, 0); va[q][1] = LDH(hp, q, 1); }
#pragma unroll
            for (int bt = 0; bt < 4; ++bt) {
                if (bt < 3) {
#pragma unroll
                    for (int q = 0; q < 8; ++q) {
                        int jn = (bt + 1) * 8 + q;
                        if (bt & 1) { va[q][0] = LDH(hp, jn, 0); va[q][1] = LDH(hp, jn, 1); }
                        else        { vb[q][0] = LDH(hp, jn, 0); vb[q][1] = LDH(hp, jn, 1); }
                    }
                }
#pragma unroll
                for (int q = 0; q < 8; ++q) {
                    int j = bt * 8 + q;
                    unsigned long long x0 = (bt & 1) ? vb[q][0] : va[q][0];
                    unsigned long long x1 = (bt & 1) ? vb[q][1] : va[q][1];
                    while (x0 == SENT || x1 == SENT) { x0 = LDH(hp, j, 0); x1 = LDH(hp, j, 1); }
                    union { unsigned long long u[2]; half8 h; } ua; ua.u[0] = x0; ua.u[1] = x1;
                    int k2 = kb + j * 64 + kg * 16;
                    half8 b0 = *(half8*)((char*)Wl + wb0 + (k2 ^ swz));
                    half8 b1 = *(half8*)((char*)Wl + wb1 + (k2 ^ swz));
                    acc0 = __builtin_amdgcn_mfma_f32_16x16x32_f16(ua.h, b0, acc0, 0, 0, 0);
                    acc1 = __builtin_amdgcn_mfma_f32_16x16x32_f16(ua.h, b1, acc1, 0, 0, 0);
                }
            }
            // partials to LDS, stride 33 (2-way banks on both write and read)
#pragma unroll
            for (int r = 0; r < 4; ++r) {
                part[w][(kg * 4 + r) * 33 + ln15] = acc0[r];
                part[w][(kg * 4 + r) * 33 + 16 + ln15] = acc1[r];
            }
        }

        float s0 = 0.f, s1 = 0.f, s2 = 0.f, s3 = 0.f;
        if (s > 0) {
            __syncthreads();
            const float* p0 = &part[2 * rp][rrow * 33 + rc4];
            const float* p1 = &part[2 * rp + 1][rrow * 33 + rc4];
            s0 = p0[0] + p1[0]; s1 = p0[1] + p1[1];
            s2 = p0[2] + p1[2]; s3 = p0[3] + p1[3];
            __syncthreads();  // WAR guard before next step's part writes
        }
        float o0 = tanhf(s0 + (float)xpv[0]);
        float o1 = tanhf(s1 + (float)xpv[1]);
        float o2 = tanhf(s2 + (float)xpv[2]);
        float o3 = tanhf(s3 + (float)xpv[3]);

        // orders poison(slot) before that slot's next h-store; waits only old stores
        asm volatile("s_waitcnt vmcnt(0)" ::: "memory");
        if (s < TSTEPS - 1) {
            union { half4v h; unsigned long long u; } pk;
            pk.h[0] = (_Float16)o0; pk.h[1] = (_Float16)o1;
            pk.h[2] = (_Float16)o2; pk.h[3] = (_Float16)o3;
            __hip_atomic_store((unsigned long long*)(ring + (size_t)(s & 7) * STEP + oidx),
                               pk.u, __ATOMIC_RELAXED, __HIP_MEMORY_SCOPE_AGENT);
            __hip_atomic_store((unsigned long long*)(ring + (size_t)((s + 4) & 7) * STEP + oidx),
                               SENT, __ATOMIC_RELAXED, __HIP_MEMORY_SCOPE_AGENT);
        } else {
            float4v f = {o0, o1, o2, o3};
            *(float4v*)(hlast + oidx) = f;
        }
    }
}

// ---------------- head ----------------
__global__ __launch_bounds__(64) void fc1_kernel(const float* __restrict__ hlast,
                                                 const float* __restrict__ w,
                                                 const float* __restrict__ b,
                                                 float* __restrict__ z) {
    int bb = blockIdx.x;
    int j = blockIdx.y * 64 + threadIdx.x;
    const float* hr = hlast + (long)bb * HID;
    const float* wr = w + (long)j * HID;
    float acc = 0.f;
    for (int k = 0; k < HID; k += 4) {
        float4v hv = *(const float4v*)(hr + k);
        float4v wv = *(const float4v*)(wr + k);
        acc += hv[0] * wv[0] + hv[1] * wv[1] + hv[2] * wv[2] + hv[3] * wv[3];
    }
    acc += b[j];
    z[bb * 256 + j] = fmaxf(acc, 0.f);
}

__global__ __launch_bounds__(256) void fc2_kernel(const float* __restrict__ z,
                                                  const float* __restrict__ w,
                                                  const float* __restrict__ b,
                                                  float* __restrict__ out) {
    __shared__ float red[4];
    int bb = blockIdx.x;
    int tid = threadIdx.x;
    float zv = z[bb * 256 + tid];
    for (int c = 0; c < 3; ++c) {
        float s = zv * w[c * 256 + tid];
        for (int off = 32; off > 0; off >>= 1) s += __shfl_down(s, off, 64);
        if ((tid & 63) == 0) red[tid >> 6] = s;
        __syncthreads();
        if (tid == 0) out[bb * 3 + c] = red[0] + red[1] + red[2] + red[3] + b[c];
        __syncthreads();
    }
}

// ---------------- launch ----------------
extern "C" void kernel_launch(void* const* d_in, const int* in_sizes, int n_in,
                              void* d_out, int out_size, void* d_ws, size_t ws_size,
                              hipStream_t stream) {
    const int*   x    = (const int*)d_in[0];
    const float* emb  = (const float*)d_in[1];
    const float* Wih  = (const float*)d_in[2];
    const float* Whh  = (const float*)d_in[3];
    const float* bih  = (const float*)d_in[4];
    const float* bhh  = (const float*)d_in[5];
    const float* fc1w = (const float*)d_in[6];
    const float* fc1b = (const float*)d_in[7];
    const float* fc2w = (const float*)d_in[8];
    const float* fc2b = (const float*)d_in[9];
    float* out = (float*)d_out;

    char* ws = (char*)d_ws;
    size_t off = 0;
    _Float16* xbias = (_Float16*)(ws + off); off += (size_t)TSTEPS * BATCH * HID * 2;  // 134.2 MB
    _Float16* wih16 = (_Float16*)(ws + off); off += (size_t)HID * EMBD * 2;            // 8 MB
    _Float16* whh16 = (_Float16*)(ws + off); off += (size_t)HID * HID * 2;             // 8 MB
    float*    bias  = (float*)(ws + off);    off += (size_t)HID * 4;
    _Float16* ring  = (_Float16*)(ws + off); off += 8 * STEP * 2;                      // 4 MB
    float*    hlast = (float*)(ws + off);    off += (size_t)BATCH * HID * 4;
    float*    z     = (float*)(ws + off);    off += (size_t)BATCH * 256 * 4;

    // pre-poison the h ring (sentinel = 0xFF bytes)
    hipMemsetAsync(ring, 0xFF, 8 * STEP * 2, stream);

    cast_f16_kernel<<<4096, 256, 0, stream>>>(Wih, wih16, HID * EMBD);
    cast_f16_kernel<<<4096, 256, 0, stream>>>(Whh, whh16, HID * HID);
    bias_kernel<<<8, 256, 0, stream>>>(bih, bhh, bias);

    phaseA_kernel<<<4096, 256, 0, stream>>>(x, emb, wih16, bias, xbias);

    void* args[] = {(void*)&xbias, (void*)&whh16, (void*)&ring, (void*)&hlast};
    hipLaunchCooperativeKernel((const void*)scan_kernel, dim3(256), dim3(256), args, 0, stream);

    fc1_kernel<<<dim3(128, 4), 64, 0, stream>>>(hlast, fc1w, fc1b, z);
    fc2_kernel<<<BATCH, 256, 0, stream>>>(z, fc2w, fc2b, out);
}

// Round 9
// 2531.538 us; speedup vs baseline: 1.8535x; 1.1899x over previous
//
#include <hip/hip_runtime.h>

typedef _Float16 half8 __attribute__((ext_vector_type(8)));
typedef _Float16 half4v __attribute__((ext_vector_type(4)));
typedef float float4v __attribute__((ext_vector_type(4)));

#define HID 2048
#define EMBD 2048
#define BATCH 128
#define TSTEPS 256
#define STEP ((size_t)BATCH * HID)

// ---------------- small prep kernels ----------------
__global__ __launch_bounds__(256) void cast_f16_kernel(const float* __restrict__ src,
                                                       _Float16* __restrict__ dst, int n) {
    int i = (blockIdx.x * 256 + threadIdx.x) * 4;
    int stride = gridDim.x * 256 * 4;
    for (; i < n; i += stride) {
        float4v v = *(const float4v*)(src + i);
        half4v h;
        h[0] = (_Float16)v[0]; h[1] = (_Float16)v[1];
        h[2] = (_Float16)v[2]; h[3] = (_Float16)v[3];
        *(half4v*)(dst + i) = h;
    }
}

__global__ __launch_bounds__(256) void bias_kernel(const float* __restrict__ a,
                                                   const float* __restrict__ b,
                                                   float* __restrict__ dst) {
    int i = blockIdx.x * 256 + threadIdx.x;
    if (i < HID) dst[i] = a[i] + b[i];
}

// ---------------- Phase A: slots 1..256 of xb = gather(emb,x) @ W_ih^T + bias ----------
__global__ __launch_bounds__(256) void phaseA_kernel(const int* __restrict__ x,
                                                     const float* __restrict__ emb,
                                                     const _Float16* __restrict__ w16,
                                                     const float* __restrict__ bias,
                                                     _Float16* __restrict__ xproj) {
    __shared__ __align__(16) _Float16 As[128 * 64];
    __shared__ __align__(16) _Float16 Bs[128 * 64];

    const int tid = threadIdx.x;
    const int bx  = blockIdx.x;
    const int nt = bx & 15, mt = bx >> 4;
    const long m0 = (long)mt * 128;
    const long n0 = (long)nt * 128;
    const int lane = tid & 63, w = tid >> 6;
    const int ln15 = lane & 15, kg = lane >> 4;
    const int wr = (w >> 1) * 64, wc = (w & 1) * 64;

    int xr[4];
#pragma unroll
    for (int it = 0; it < 4; ++it) xr[it] = x[m0 + ((it * 256 + tid) >> 3)];

    float4v acc[4][4];
#pragma unroll
    for (int m = 0; m < 4; ++m)
#pragma unroll
        for (int n = 0; n < 4; ++n) acc[m][n] = (float4v){0.f, 0.f, 0.f, 0.f};

    for (int kt = 0; kt < 32; ++kt) {
        __syncthreads();
#pragma unroll
        for (int it = 0; it < 4; ++it) {
            int c = it * 256 + tid;
            const float* src = emb + (long)xr[it] * EMBD + kt * 64 + (c & 7) * 8;
            float4v v0 = *(const float4v*)src;
            float4v v1 = *(const float4v*)(src + 4);
            half8 hv;
#pragma unroll
            for (int q = 0; q < 4; ++q) { hv[q] = (_Float16)v0[q]; hv[4 + q] = (_Float16)v1[q]; }
            *(half8*)(&As[c * 8]) = hv;
        }
#pragma unroll
        for (int it = 0; it < 4; ++it) {
            int c = it * 256 + tid;
            const _Float16* src = w16 + (n0 + (c >> 3)) * (long)EMBD + kt * 64 + (c & 7) * 8;
            *(half8*)(&Bs[c * 8]) = *(const half8*)src;
        }
        __syncthreads();
#pragma unroll
        for (int kk = 0; kk < 2; ++kk) {
            half8 a[4], b[4];
#pragma unroll
            for (int m = 0; m < 4; ++m)
                a[m] = *(half8*)(&As[(wr + m * 16 + ln15) * 64 + kk * 32 + kg * 8]);
#pragma unroll
            for (int n = 0; n < 4; ++n)
                b[n] = *(half8*)(&Bs[(wc + n * 16 + ln15) * 64 + kk * 32 + kg * 8]);
            // swapped operands -> transposed fragment: lane holds 4 consecutive cols
#pragma unroll
            for (int m = 0; m < 4; ++m)
#pragma unroll
                for (int n = 0; n < 4; ++n)
                    acc[m][n] = __builtin_amdgcn_mfma_f32_16x16x32_f16(b[n], a[m], acc[m][n], 0, 0, 0);
        }
    }
#pragma unroll
    for (int m = 0; m < 4; ++m) {
        long mg = m0 + wr + m * 16 + ln15;
#pragma unroll
        for (int n = 0; n < 4; ++n) {
            int nb = (int)n0 + wc + n * 16 + kg * 4;
            float4v bv = *(const float4v*)(bias + nb);
            union { half4v h; unsigned long long u; } pk;
#pragma unroll
            for (int r = 0; r < 4; ++r) pk.h[r] = (_Float16)(acc[m][n][r] + bv[r]);
            *(unsigned long long*)(xproj + mg * HID + nb) = pk.u;
        }
    }
}

// ---------------- Phase B: persistent scan — flag gate + cacheable L2-shared h ------
// 256 blocks x 256 thr. gid=bx&3 owns rows [32g,+32); sub=bx>>2 owns cols [32c,+32).
// Wave (pr=w>>1, kh=w&1): 16 rows x 32 cols x k-half; LDS part-reduce (stride 33).
// Buffer xb = 257 slots. bias[s] lives in slot s+1 (read sc1 -> never cached).
// h_{s+1} (end of step s) stored sc1 into slot s (= bias[s-1]'s home; dead: every
// group mate read bias[s-1] before posting flag_s, which the storer's gate_s saw).
// Consumers at step s gate on all 64 group flags >= s, then read h_s from slot s-1
// with PLAIN CACHEABLE loads: addresses written once, never cacheably touched
// pre-gate, L2s invalidated at dispatch => first-touch fetches h from L3, then the
// XCD's L2 serves all 32 co-resident group blocks (the R8 L3-storm, eliminated).
__global__ __launch_bounds__(256, 1) void scan_kernel(_Float16* __restrict__ xb,
                                                      const _Float16* __restrict__ whh,
                                                      float* __restrict__ hlast,
                                                      unsigned* __restrict__ flags) {
    __shared__ __align__(16) _Float16 Wl[32 * 2048];  // 128 KB
    __shared__ float part[4][16 * 33];

    const int tid = threadIdx.x;
    const int bx = blockIdx.x;
    const int gid = bx & 3, sub = bx >> 2;
    const int m0 = gid * 32, n0 = sub * 32;
    const int lane = tid & 63, w = tid >> 6;
    const int ln15 = lane & 15, kg = lane >> 4;
    const int pr = w >> 1, kh = w & 1;

    // stage W[n0..n0+32) x [0..2048): byte = col*4096 + ((k*2) ^ ((col&7)<<4))
    for (int it = 0; it < 32; ++it) {
        int c = it * 256 + tid;
        int col = c >> 8, ch = c & 255;
        half8 v = *(const half8*)(whh + (long)(n0 + col) * HID + ch * 8);
        *(half8*)((char*)Wl + col * 4096 + ((ch * 16) ^ ((col & 7) << 4))) = v;
    }
    __syncthreads();

    unsigned* gfl = flags + gid * 64;                       // 64 flags per group
    const unsigned long long* gfl64 = (const unsigned long long*)gfl;
    const size_t arow = (size_t)(m0 + pr * 16 + ln15);      // h row this lane loads
    const int wb0 = ln15 * 4096, wb1 = (16 + ln15) * 4096;  // W LDS row bases
    const int swz = (ln15 & 7) << 4;
    const int kb = kh * 2048;                               // k-half byte offset
    const int rp = tid >> 7, ridx = tid & 127;              // reduce/output mapping
    const int rrow = ridx >> 3, rc4 = (ridx & 7) * 4;
    const size_t oidx = (size_t)(m0 + rp * 16 + rrow) * HID + n0 + rc4;

    for (int s = 0; s < TSTEPS; ++s) {
        // bias[s] from slot s+1 — sc1 bypass (keeps slot out of all caches)
        unsigned long long xbits = __hip_atomic_load(
            (const unsigned long long*)(xb + (size_t)(s + 1) * STEP + oidx),
            __ATOMIC_RELAXED, __HIP_MEMORY_SCOPE_AGENT);

        float4v acc0 = (float4v){0.f, 0.f, 0.f, 0.f};
        float4v acc1 = (float4v){0.f, 0.f, 0.f, 0.f};
        if (s > 0) {
            // ---- gate: all 64 producer flags of this group >= s (paced sc1 poll)
            for (;;) {
                bool ok = true;
                if (lane < 32) {
                    unsigned long long v = __hip_atomic_load(gfl64 + lane,
                                            __ATOMIC_RELAXED, __HIP_MEMORY_SCOPE_AGENT);
                    ok = ((unsigned)v >= (unsigned)s) && ((unsigned)(v >> 32) >= (unsigned)s);
                }
                if (__all(ok)) break;
                __builtin_amdgcn_s_sleep(2);
            }
            asm volatile("" ::: "memory");        // no hoisting h loads above gate
            __builtin_amdgcn_sched_barrier(0);

            // ---- h_s from slot s-1: plain cacheable loads (L2-shared per XCD)
            const _Float16* hrow = xb + (size_t)(s - 1) * STEP + arow * HID + kh * 1024;
#pragma unroll
            for (int j = 0; j < 32; ++j) {
                half8 a = *(const half8*)(hrow + j * 32 + kg * 8);
                int k2 = kb + j * 64 + kg * 16;
                half8 b0 = *(half8*)((char*)Wl + wb0 + (k2 ^ swz));
                half8 b1 = *(half8*)((char*)Wl + wb1 + (k2 ^ swz));
                acc0 = __builtin_amdgcn_mfma_f32_16x16x32_f16(a, b0, acc0, 0, 0, 0);
                acc1 = __builtin_amdgcn_mfma_f32_16x16x32_f16(a, b1, acc1, 0, 0, 0);
            }
            // partials to LDS (stride 33)
#pragma unroll
            for (int r = 0; r < 4; ++r) {
                part[w][(kg * 4 + r) * 33 + ln15] = acc0[r];
                part[w][(kg * 4 + r) * 33 + 16 + ln15] = acc1[r];
            }
        }

        float s0 = 0.f, s1 = 0.f, s2 = 0.f, s3 = 0.f;
        if (s > 0) {
            __syncthreads();
            const float* p0 = &part[2 * rp][rrow * 33 + rc4];
            const float* p1 = &part[2 * rp + 1][rrow * 33 + rc4];
            s0 = p0[0] + p1[0]; s1 = p0[1] + p1[1];
            s2 = p0[2] + p1[2]; s3 = p0[3] + p1[3];
        }
        union { unsigned long long u; half4v h; } xbv; xbv.u = xbits;
        float o0 = tanhf(s0 + (float)xbv.h[0]);
        float o1 = tanhf(s1 + (float)xbv.h[1]);
        float o2 = tanhf(s2 + (float)xbv.h[2]);
        float o3 = tanhf(s3 + (float)xbv.h[3]);

        if (s < TSTEPS - 1) {
            // h_{s+1} -> slot s (sc1 fire-and-forget)
            union { half4v h; unsigned long long u; } pk;
            pk.h[0] = (_Float16)o0; pk.h[1] = (_Float16)o1;
            pk.h[2] = (_Float16)o2; pk.h[3] = (_Float16)o3;
            __hip_atomic_store((unsigned long long*)(xb + (size_t)s * STEP + oidx),
                               pk.u, __ATOMIC_RELAXED, __HIP_MEMORY_SCOPE_AGENT);
            // syncthreads drains vmcnt (compiler emits vmcnt(0) before s_barrier):
            // all 256 threads' h stores are at L3 before the flag. Also the WAR
            // guard for part[].
            __syncthreads();
            if (tid == 0)
                __hip_atomic_store(&gfl[sub], (unsigned)(s + 1),
                                   __ATOMIC_RELAXED, __HIP_MEMORY_SCOPE_AGENT);
        } else {
            float4v f = {o0, o1, o2, o3};
            *(float4v*)(hlast + oidx) = f;
        }
    }
}

// ---------------- head ----------------
__global__ __launch_bounds__(64) void fc1_kernel(const float* __restrict__ hlast,
                                                 const float* __restrict__ w,
                                                 const float* __restrict__ b,
                                                 float* __restrict__ z) {
    int bb = blockIdx.x;
    int j = blockIdx.y * 64 + threadIdx.x;
    const float* hr = hlast + (long)bb * HID;
    const float* wr = w + (long)j * HID;
    float acc = 0.f;
    for (int k = 0; k < HID; k += 4) {
        float4v hv = *(const float4v*)(hr + k);
        float4v wv = *(const float4v*)(wr + k);
        acc += hv[0] * wv[0] + hv[1] * wv[1] + hv[2] * wv[2] + hv[3] * wv[3];
    }
    acc += b[j];
    z[bb * 256 + j] = fmaxf(acc, 0.f);
}

__global__ __launch_bounds__(256) void fc2_kernel(const float* __restrict__ z,
                                                  const float* __restrict__ w,
                                                  const float* __restrict__ b,
                                                  float* __restrict__ out) {
    __shared__ float red[4];
    int bb = blockIdx.x;
    int tid = threadIdx.x;
    float zv = z[bb * 256 + tid];
    for (int c = 0; c < 3; ++c) {
        float s = zv * w[c * 256 + tid];
        for (int off = 32; off > 0; off >>= 1) s += __shfl_down(s, off, 64);
        if ((tid & 63) == 0) red[tid >> 6] = s;
        __syncthreads();
        if (tid == 0) out[bb * 3 + c] = red[0] + red[1] + red[2] + red[3] + b[c];
        __syncthreads();
    }
}

// ---------------- launch ----------------
extern "C" void kernel_launch(void* const* d_in, const int* in_sizes, int n_in,
                              void* d_out, int out_size, void* d_ws, size_t ws_size,
                              hipStream_t stream) {
    const int*   x    = (const int*)d_in[0];
    const float* emb  = (const float*)d_in[1];
    const float* Wih  = (const float*)d_in[2];
    const float* Whh  = (const float*)d_in[3];
    const float* bih  = (const float*)d_in[4];
    const float* bhh  = (const float*)d_in[5];
    const float* fc1w = (const float*)d_in[6];
    const float* fc1b = (const float*)d_in[7];
    const float* fc2w = (const float*)d_in[8];
    const float* fc2b = (const float*)d_in[9];
    float* out = (float*)d_out;

    char* ws = (char*)d_ws;
    size_t off = 0;
    _Float16* xb    = (_Float16*)(ws + off); off += 257 * STEP * 2;         // 134.7 MB
    _Float16* wih16 = (_Float16*)(ws + off); off += (size_t)HID * EMBD * 2; // 8 MB
    _Float16* whh16 = (_Float16*)(ws + off); off += (size_t)HID * HID * 2;  // 8 MB
    float*    bias  = (float*)(ws + off);    off += (size_t)HID * 4;
    float*    hlast = (float*)(ws + off);    off += (size_t)BATCH * HID * 4;
    float*    z     = (float*)(ws + off);    off += (size_t)BATCH * 256 * 4;
    unsigned* flags = (unsigned*)(ws + off); off += 4 * 64 * 4;  // 1 KB

    hipMemsetAsync(flags, 0, 4 * 64 * 4, stream);

    cast_f16_kernel<<<4096, 256, 0, stream>>>(Wih, wih16, HID * EMBD);
    cast_f16_kernel<<<4096, 256, 0, stream>>>(Whh, whh16, HID * HID);
    bias_kernel<<<8, 256, 0, stream>>>(bih, bhh, bias);

    // phaseA writes bias[s] into slot s+1
    phaseA_kernel<<<4096, 256, 0, stream>>>(x, emb, wih16, bias, xb + STEP);

    void* args[] = {(void*)&xb, (void*)&whh16, (void*)&hlast, (void*)&flags};
    hipLaunchCooperativeKernel((const void*)scan_kernel, dim3(256), dim3(256), args, 0, stream);

    fc1_kernel<<<dim3(128, 4), 64, 0, stream>>>(hlast, fc1w, fc1b, z);
    fc2_kernel<<<BATCH, 256, 0, stream>>>(z, fc2w, fc2b, out);
}